// Round 16
// baseline (410.649 us; speedup 1.0000x reference)
//
#include <hip/hip_runtime.h>

namespace {
constexpr int kB = 512;
constexpr int kT = 200;
constexpr int kI = 784;
constexpr int kH = 128;
constexpr int kO = 10;
constexpr int kM = kB * kT;  // 102400 rows
constexpr float kBeta = 0.9f;
constexpr float kThr = 1.0f;
}  // namespace

// ---------------------------------------------------------------------------
// Transpose W[N][K] -> WT[K][N]. 16x16 LDS tile. Proven r10/r12.
// ---------------------------------------------------------------------------
__global__ __launch_bounds__(256) void transposeW(const float* __restrict__ W,
                                                  float* __restrict__ WT,
                                                  int N, int K) {
  __shared__ float t[16][17];
  const int k0 = blockIdx.x * 16, n0 = blockIdx.y * 16;
  const int tx = threadIdx.x & 15, ty = threadIdx.x >> 4;
  t[ty][tx] = W[(size_t)(n0 + ty) * K + k0 + tx];
  __syncthreads();
  WT[(size_t)(k0 + ty) * N + n0 + tx] = t[tx][ty];
}

// K-slice table. NSPLIT=2/K=784 keeps r12's exact {0,400},{400,384}.
template <int KSTRIDE, int NSPLIT>
__device__ __forceinline__ void split_range(int part, int& kbeg,
                                            int& nsteps) {
  if (NSPLIT == 1) {
    kbeg = 0;
    nsteps = KSTRIDE / 16;
  } else if (NSPLIT == 2) {
    if (KSTRIDE == 784) {
      kbeg = part ? 400 : 0;
      nsteps = part ? 24 : 25;
    } else {
      kbeg = part * (KSTRIDE / 2);
      nsteps = KSTRIDE / 32;
    }
  } else {  // NSPLIT == 4, KSTRIDE == 784: 192+192+192+208
    kbeg = part * 192;
    nsteps = (part == 3) ? 13 : 12;
  }
}

// ---------------------------------------------------------------------------
// C[M][128] = A[M][K-slice] . BT[K-slice][128] (+ bias); BT = W^T (k-major).
// r12's proven kernel (64x128 tile, 128 threads, 8x8 per-thread, BK=16,
// single LDS buffer, two barriers/step, VGPR 52, GEMM1 273us) — body
// verbatim; only the part decode generalizes to NSPLIT in {1,2,4}.
// Part p writes raw partials to C + p*coff. Ascending-k per part ->
// same accumulation class proven absmax-0.0 since r7.
// ---------------------------------------------------------------------------
template <int KSTRIDE, int NSPLIT>
__global__ __launch_bounds__(128, 4) void gemm64bt(
    const float* __restrict__ A, const float* __restrict__ BT,
    const float* __restrict__ bias, float* __restrict__ C, size_t coff) {
  constexpr int BM = 64, BK = 16;
  __shared__ float As[BK][68];
  __shared__ float Bs[BK][132];
  const int tid = threadIdx.x;
  const int tx = tid & 15;   // n-dim 0..15
  const int ty = tid >> 4;   // m-dim 0..7
  int tile, part;
  if (NSPLIT == 1) {
    tile = blockIdx.x;
    part = 0;
  } else if (NSPLIT == 2) {
    tile = blockIdx.x >> 1;
    part = blockIdx.x & 1;
  } else {
    tile = blockIdx.x >> 2;
    part = blockIdx.x & 3;
  }
  int kbeg, nsteps;
  split_range<KSTRIDE, NSPLIT>(part, kbeg, nsteps);
  C += (size_t)part * coff;
  const int row0 = tile * BM;

  // A staging: 64 rows x 16 k, thread -> 2 rows, 4 k each (r12 verbatim).
  const int ar0 = tid >> 2;        // 0..31
  const int ar1 = ar0 + 32;
  const int ac4 = (tid & 3) * 4;
  // B staging from BT (k-major): coalesced b128 loads + b128 ds_writes.
  const int sbk = tid >> 5;        // 0..3
  const int sbn4 = (tid & 31) * 4; // 0..124

  const float* aptr = A + (size_t)(row0 + ar0) * KSTRIDE + kbeg + ac4;
  const float* btptr = BT + (size_t)(kbeg + sbk) * 128 + sbn4;

  float acc[8][8];
#pragma unroll
  for (int i = 0; i < 8; ++i)
#pragma unroll
    for (int j = 0; j < 8; ++j) acc[i][j] = 0.0f;

  for (int s = 0; s < nsteps; ++s) {
    const int k0 = s * BK;
    __syncthreads();
    {
      const float4 va0 = *reinterpret_cast<const float4*>(aptr + k0);
      const float4 va1 = *reinterpret_cast<const float4*>(
          aptr + (size_t)32 * KSTRIDE + k0);
      As[ac4 + 0][ar0] = va0.x; As[ac4 + 1][ar0] = va0.y;
      As[ac4 + 2][ar0] = va0.z; As[ac4 + 3][ar0] = va0.w;
      As[ac4 + 0][ar1] = va1.x; As[ac4 + 1][ar1] = va1.y;
      As[ac4 + 2][ar1] = va1.z; As[ac4 + 3][ar1] = va1.w;
#pragma unroll
      for (int l = 0; l < 4; ++l) {
        const float4 vb = *reinterpret_cast<const float4*>(
            btptr + (size_t)(k0 + l * 4) * 128);
        *reinterpret_cast<float4*>(&Bs[sbk + l * 4][sbn4]) = vb;
      }
    }
    __syncthreads();
#pragma unroll
    for (int kk = 0; kk < BK; ++kk) {
      float a[8], b[8];
      *reinterpret_cast<float4*>(&a[0]) =
          *reinterpret_cast<const float4*>(&As[kk][ty * 4]);
      *reinterpret_cast<float4*>(&a[4]) =
          *reinterpret_cast<const float4*>(&As[kk][32 + ty * 4]);
      *reinterpret_cast<float4*>(&b[0]) =
          *reinterpret_cast<const float4*>(&Bs[kk][tx * 4]);
      *reinterpret_cast<float4*>(&b[4]) =
          *reinterpret_cast<const float4*>(&Bs[kk][64 + tx * 4]);
#pragma unroll
      for (int i = 0; i < 8; ++i)
#pragma unroll
        for (int j = 0; j < 8; ++j) acc[i][j] = fmaf(a[i], b[j], acc[i][j]);
    }
  }

#pragma unroll
  for (int i = 0; i < 8; ++i) {
    const int m = (i < 4) ? (ty * 4 + i) : (32 + ty * 4 + (i - 4));
    const size_t r = (size_t)(row0 + m);
#pragma unroll
    for (int jh = 0; jh < 2; ++jh) {
      const int n = jh * 64 + tx * 4;
      float4 v;
      v.x = acc[i][jh * 4 + 0];
      v.y = acc[i][jh * 4 + 1];
      v.z = acc[i][jh * 4 + 2];
      v.w = acc[i][jh * 4 + 3];
      if (bias != nullptr) {
        v.x += bias[n + 0];
        v.y += bias[n + 1];
        v.z += bias[n + 2];
        v.w += bias[n + 3];
      }
      *reinterpret_cast<float4*>(&C[r * 128 + n]) = v;
    }
  }
}

#define LIF_STEP(mm, ss, curexpr)                                      \
  {                                                                    \
    const float cur_ = (curexpr);                                      \
    mm = __fsub_rn(__fadd_rn(__fmul_rn(kBeta, mm), cur_), ss);         \
    ss = (mm > kThr) ? 1.0f : 0.0f;                                    \
  }

// ---------------------------------------------------------------------------
// 2-input LIF combine scan: cur = (Q0+Q1)+bias; spikes -> Q0. (r12 verbatim)
// ---------------------------------------------------------------------------
__global__ __launch_bounds__(128) void lif_scan13(
    float* __restrict__ P0, const float* __restrict__ P1,
    const float* __restrict__ b1) {
  const int g = blockIdx.x * 128 + threadIdx.x;  // 0..32767
  const int b = g >> 6;
  const int h2 = (g & 63) * 2;
  const size_t base = (size_t)b * kT * 128 + h2;
  const float bb0 = b1[h2], bb1 = b1[h2 + 1];
#define LD0(t) (*reinterpret_cast<const float2*>(&P0[base + (size_t)(t)*128]))
#define LD1(t) (*reinterpret_cast<const float2*>(&P1[base + (size_t)(t)*128]))
  float2 cA0 = LD0(0), cA1 = LD1(0), cB0 = LD0(1), cB1 = LD1(1);
  float2 cC0 = LD0(2), cC1 = LD1(2), cD0 = LD0(3), cD1 = LD1(3);
  float m0 = 0.f, m1 = 0.f, s0 = 0.f, s1 = 0.f;
  for (int t = 0; t < kT; t += 2) {
    const int pa = (t + 4 < kT) ? t + 4 : kT - 1;
    const int pb = (t + 5 < kT) ? t + 5 : kT - 1;
    const float2 nA0 = LD0(pa), nA1 = LD1(pa);
    const float2 nB0 = LD0(pb), nB1 = LD1(pb);
    LIF_STEP(m0, s0, __fadd_rn(__fadd_rn(cA0.x, cA1.x), bb0));
    LIF_STEP(m1, s1, __fadd_rn(__fadd_rn(cA0.y, cA1.y), bb1));
    *reinterpret_cast<float2*>(&P0[base + (size_t)t * 128]) =
        make_float2(s0, s1);
    LIF_STEP(m0, s0, __fadd_rn(__fadd_rn(cB0.x, cB1.x), bb0));
    LIF_STEP(m1, s1, __fadd_rn(__fadd_rn(cB0.y, cB1.y), bb1));
    *reinterpret_cast<float2*>(&P0[base + (size_t)(t + 1) * 128]) =
        make_float2(s0, s1);
    cA0 = cC0; cA1 = cC1; cB0 = cD0; cB1 = cD1;
    cC0 = nA0; cC1 = nA1; cD0 = nB0; cD1 = nB1;
  }
#undef LD0
#undef LD1
}

// ---------------------------------------------------------------------------
// 4-input LIF combine scan: cur = (((P0+P1)+P2)+P3)+bias; spikes -> P0.
// Depth-2 load pipeline (8 float2 in flight -> ~8KB/CU).
// ---------------------------------------------------------------------------
__global__ __launch_bounds__(128) void lif_scan13_4(
    float* __restrict__ P0, const float* __restrict__ P1,
    const float* __restrict__ P2, const float* __restrict__ P3,
    const float* __restrict__ b1) {
  const int g = blockIdx.x * 128 + threadIdx.x;  // 0..32767
  const int b = g >> 6;
  const int h2 = (g & 63) * 2;
  const size_t base = (size_t)b * kT * 128 + h2;
  const float bb0 = b1[h2], bb1 = b1[h2 + 1];
#define LDP(P, t) (*reinterpret_cast<const float2*>(&P[base + (size_t)(t)*128]))
  float2 a0 = LDP(P0, 0), a1 = LDP(P1, 0), a2 = LDP(P2, 0), a3 = LDP(P3, 0);
  float2 e0 = LDP(P0, 1), e1 = LDP(P1, 1), e2 = LDP(P2, 1), e3 = LDP(P3, 1);
  float m0 = 0.f, m1 = 0.f, s0 = 0.f, s1 = 0.f;
  for (int t = 0; t < kT; ++t) {
    const int pn = (t + 2 < kT) ? t + 2 : kT - 1;
    const float2 n0 = LDP(P0, pn), n1 = LDP(P1, pn);
    const float2 n2 = LDP(P2, pn), n3 = LDP(P3, pn);
    LIF_STEP(m0, s0,
             __fadd_rn(__fadd_rn(__fadd_rn(__fadd_rn(a0.x, a1.x), a2.x),
                                 a3.x), bb0));
    LIF_STEP(m1, s1,
             __fadd_rn(__fadd_rn(__fadd_rn(__fadd_rn(a0.y, a1.y), a2.y),
                                 a3.y), bb1));
    *reinterpret_cast<float2*>(&P0[base + (size_t)t * 128]) =
        make_float2(s0, s1);
    a0 = e0; a1 = e1; a2 = e2; a3 = e3;
    e0 = n0; e1 = n1; e2 = n2; e3 = n3;
  }
#undef LDP
}

// ---------------------------------------------------------------------------
// Layer-2 LIF scan, in place (fallback path). (r12 verbatim)
// ---------------------------------------------------------------------------
__global__ __launch_bounds__(128) void lif_scan2(float* __restrict__ buf) {
  const int g = blockIdx.x * 128 + threadIdx.x;  // 0..32767
  const int b = g >> 6;
  const int h2 = (g & 63) * 2;
  const size_t base = (size_t)b * kT * 128 + h2;
#define LD(t) (*reinterpret_cast<const float2*>(&buf[base + (size_t)(t)*128]))
  float2 cA = LD(0), cB = LD(1), cC = LD(2), cD = LD(3);
  float m0 = 0.f, m1 = 0.f, s0 = 0.f, s1 = 0.f;
  for (int t = 0; t < kT; t += 2) {
    const int pa = (t + 4 < kT) ? t + 4 : kT - 1;
    const int pb = (t + 5 < kT) ? t + 5 : kT - 1;
    const float2 nA = LD(pa), nB = LD(pb);
    LIF_STEP(m0, s0, cA.x);
    LIF_STEP(m1, s1, cA.y);
    *reinterpret_cast<float2*>(&buf[base + (size_t)t * 128]) =
        make_float2(s0, s1);
    LIF_STEP(m0, s0, cB.x);
    LIF_STEP(m1, s1, cB.y);
    *reinterpret_cast<float2*>(&buf[base + (size_t)(t + 1) * 128]) =
        make_float2(s0, s1);
    cA = cC; cB = cD; cC = nA; cD = nB;
  }
#undef LD
}

// ---------------------------------------------------------------------------
// GEMM3: cur3[M][10] = s2[M][128] . W3[10][128]^T + b3. (unchanged)
// ---------------------------------------------------------------------------
__global__ __launch_bounds__(320) void gemm3_n10(
    const float* __restrict__ A, const float* __restrict__ W3,
    const float* __restrict__ b3, float* __restrict__ C) {
  __shared__ float Ss[64][132];
  __shared__ float Ws[10][132];
  __shared__ float bs[10];
  const int tid = threadIdx.x;
  const size_t row0 = (size_t)blockIdx.x * 64;

  {
    const int r = tid >> 5;
    const int c4 = (tid & 31) * 4;
    const float4 v = *reinterpret_cast<const float4*>(&W3[r * 128 + c4]);
    Ws[r][c4 + 0] = v.x;
    Ws[r][c4 + 1] = v.y;
    Ws[r][c4 + 2] = v.z;
    Ws[r][c4 + 3] = v.w;
    if (tid < 10) bs[tid] = b3[tid];
  }
  for (int fi = tid; fi < 2048; fi += 320) {
    const int r = fi >> 5;
    const int c4 = (fi & 31) * 4;
    const float4 v =
        *reinterpret_cast<const float4*>(&A[(row0 + r) * 128 + c4]);
    Ss[r][c4 + 0] = v.x;
    Ss[r][c4 + 1] = v.y;
    Ss[r][c4 + 2] = v.z;
    Ss[r][c4 + 3] = v.w;
  }
  __syncthreads();

#pragma unroll
  for (int l = 0; l < 2; ++l) {
    const int idx = tid + l * 320;
    const int r = idx / 10;
    const int o = idx - r * 10;
    float acc = bs[o];
#pragma unroll
    for (int k = 0; k < 128; k += 4) {
      const float4 a = *reinterpret_cast<const float4*>(&Ss[r][k]);
      const float4 w = *reinterpret_cast<const float4*>(&Ws[o][k]);
      acc = fmaf(a.x, w.x, acc);
      acc = fmaf(a.y, w.y, acc);
      acc = fmaf(a.z, w.z, acc);
      acc = fmaf(a.w, w.w, acc);
    }
    C[(row0 + r) * 10 + o] = acc;
  }
}

// ---------------------------------------------------------------------------
// Output LIF scan -> out[t][b][o]. (unchanged)
// ---------------------------------------------------------------------------
__global__ __launch_bounds__(256) void lif_scan_out(
    const float* __restrict__ cur3, float* __restrict__ out) {
  const int g = blockIdx.x * 256 + threadIdx.x;  // 0..5119
  if (g >= kB * kO) return;
  const int b = g / kO;
  const int o = g - b * kO;
  float m = 0.0f, s = 0.0f;
#pragma unroll 4
  for (int t = 0; t < kT; ++t) {
    const float c = cur3[((size_t)b * kT + t) * kO + o];
    m = __fsub_rn(__fadd_rn(__fmul_rn(kBeta, m), c), s);
    s = (m > kThr) ? 1.0f : 0.0f;
    out[(size_t)t * (kB * kO) + g] = s;
  }
}

extern "C" void kernel_launch(void* const* d_in, const int* in_sizes, int n_in,
                              void* d_out, int out_size, void* d_ws,
                              size_t ws_size, hipStream_t stream) {
  (void)in_sizes;
  (void)n_in;
  (void)out_size;
  const float* x = (const float*)d_in[0];    // [B,T,784]
  const float* W1 = (const float*)d_in[1];   // [128,784]
  const float* b1 = (const float*)d_in[2];   // [128]
  const float* W2 = (const float*)d_in[3];   // [128,128]
  const float* b2 = (const float*)d_in[4];   // [128]
  const float* W3 = (const float*)d_in[5];   // [10,128]
  const float* b3 = (const float*)d_in[6];   // [10]
  float* out = (float*)d_out;                // [T,B,10] = 4.1 MB

  const size_t bufElems = (size_t)kM * kH;   // 52.4 MB each
  float* P0 = (float*)d_ws;
  float* P1 = P0 + bufElems;
  float* P2 = P1 + bufElems;
  float* P3 = P2 + bufElems;
  const bool ws4 = ws_size >= 4 * bufElems * sizeof(float);

  // W1T + W2T (467 KB) stashed at the head of d_out (overwritten at end).
  float* W1T = out;
  float* W2T = W1T + (size_t)kI * kH;

  transposeW<<<dim3(kI / 16, kH / 16), 256, 0, stream>>>(W1, W1T, kH, kI);
  transposeW<<<dim3(kH / 16, kH / 16), 256, 0, stream>>>(W2, W2T, kH, kH);

  if (ws4) {
    // Layer 1: 4-way split-K, 6400 blocks -> partials P0..P3.
    gemm64bt<kI, 4><<<4 * (kM / 64), 128, 0, stream>>>(x, W1T, nullptr, P0,
                                                       bufElems);
    lif_scan13_4<<<256, 128, 0, stream>>>(P0, P1, P2, P3, b1);  // s1 -> P0
    // Layer 2: 2-way split-K, 3200 blocks -> partials P2,P3.
    gemm64bt<kH, 2><<<2 * (kM / 64), 128, 0, stream>>>(P0, W2T, nullptr, P2,
                                                       bufElems);
    lif_scan13<<<256, 128, 0, stream>>>(P2, P3, b2);            // s2 -> P2
    // Layer 3: cur3 -> P1 (free).
    gemm3_n10<<<kM / 64, 320, 0, stream>>>(P2, W3, b3, P1);
    lif_scan_out<<<(kB * kO + 255) / 256, 256, 0, stream>>>(P1, out);
  } else {
    // Fallback: exact r12 path (2-buffer workspace).
    gemm64bt<kI, 2><<<2 * (kM / 64), 128, 0, stream>>>(x, W1T, nullptr, P0,
                                                       bufElems);
    lif_scan13<<<256, 128, 0, stream>>>(P0, P1, b1);            // s1 -> P0
    gemm64bt<kH, 1><<<kM / 64, 128, 0, stream>>>(P0, W2T, b2, P1, 0);
    lif_scan2<<<256, 128, 0, stream>>>(P1);                     // s2 -> P1
    gemm3_n10<<<kM / 64, 320, 0, stream>>>(P1, W3, b3, P0);
    lif_scan_out<<<(kB * kO + 255) / 256, 256, 0, stream>>>(P0, out);
  }
}

// Round 17
// 391.817 us; speedup vs baseline: 1.0481x; 1.0481x over previous
//
#include <hip/hip_runtime.h>

namespace {
constexpr int kB = 512;
constexpr int kT = 200;
constexpr int kI = 784;
constexpr int kH = 128;
constexpr int kO = 10;
constexpr int kM = kB * kT;  // 102400 rows
constexpr float kBeta = 0.9f;
constexpr float kThr = 1.0f;
}  // namespace

// ---------------------------------------------------------------------------
// Transpose W[N][K] -> WT[K][N]. 16x16 LDS tile. Proven r10/r12/r16.
// ---------------------------------------------------------------------------
__global__ __launch_bounds__(256) void transposeW(const float* __restrict__ W,
                                                  float* __restrict__ WT,
                                                  int N, int K) {
  __shared__ float t[16][17];
  const int k0 = blockIdx.x * 16, n0 = blockIdx.y * 16;
  const int tx = threadIdx.x & 15, ty = threadIdx.x >> 4;
  t[ty][tx] = W[(size_t)(n0 + ty) * K + k0 + tx];
  __syncthreads();
  WT[(size_t)(k0 + ty) * N + n0 + tx] = t[tx][ty];
}

// ---------------------------------------------------------------------------
// GEMM1: C[M][128] = A[M][K-slice] . BT[K-slice][128] raw partials.
// r12/r16's proven kernel (64x128 tile, 128 thr, 8x8/thread, BK=16, VGPR~56,
// 273us): 2-way split-K {0,400},{400,384}; part p -> C + p*coff.
// ---------------------------------------------------------------------------
__global__ __launch_bounds__(128, 4) void gemm64bt2(
    const float* __restrict__ A, const float* __restrict__ BT,
    float* __restrict__ C, size_t coff) {
  constexpr int BM = 64, BK = 16, KS = kI;
  __shared__ float As[BK][68];
  __shared__ float Bs[BK][132];
  const int tid = threadIdx.x;
  const int tx = tid & 15;
  const int ty = tid >> 4;
  const int tile = blockIdx.x >> 1;
  const int half = blockIdx.x & 1;
  const int kbeg = half ? 400 : 0;
  const int nsteps = half ? 24 : 25;
  if (half) C += coff;
  const int row0 = tile * BM;

  const int ar0 = tid >> 2;        // 0..31
  const int ar1 = ar0 + 32;
  const int ac4 = (tid & 3) * 4;
  const int sbk = tid >> 5;        // 0..3
  const int sbn4 = (tid & 31) * 4; // 0..124

  const float* aptr = A + (size_t)(row0 + ar0) * KS + kbeg + ac4;
  const float* btptr = BT + (size_t)(kbeg + sbk) * 128 + sbn4;

  float acc[8][8];
#pragma unroll
  for (int i = 0; i < 8; ++i)
#pragma unroll
    for (int j = 0; j < 8; ++j) acc[i][j] = 0.0f;

  for (int s = 0; s < nsteps; ++s) {
    const int k0 = s * BK;
    __syncthreads();
    {
      const float4 va0 = *reinterpret_cast<const float4*>(aptr + k0);
      const float4 va1 =
          *reinterpret_cast<const float4*>(aptr + (size_t)32 * KS + k0);
      As[ac4 + 0][ar0] = va0.x; As[ac4 + 1][ar0] = va0.y;
      As[ac4 + 2][ar0] = va0.z; As[ac4 + 3][ar0] = va0.w;
      As[ac4 + 0][ar1] = va1.x; As[ac4 + 1][ar1] = va1.y;
      As[ac4 + 2][ar1] = va1.z; As[ac4 + 3][ar1] = va1.w;
#pragma unroll
      for (int l = 0; l < 4; ++l) {
        const float4 vb = *reinterpret_cast<const float4*>(
            btptr + (size_t)(k0 + l * 4) * 128);
        *reinterpret_cast<float4*>(&Bs[sbk + l * 4][sbn4]) = vb;
      }
    }
    __syncthreads();
#pragma unroll
    for (int kk = 0; kk < BK; ++kk) {
      float a[8], b[8];
      *reinterpret_cast<float4*>(&a[0]) =
          *reinterpret_cast<const float4*>(&As[kk][ty * 4]);
      *reinterpret_cast<float4*>(&a[4]) =
          *reinterpret_cast<const float4*>(&As[kk][32 + ty * 4]);
      *reinterpret_cast<float4*>(&b[0]) =
          *reinterpret_cast<const float4*>(&Bs[kk][tx * 4]);
      *reinterpret_cast<float4*>(&b[4]) =
          *reinterpret_cast<const float4*>(&Bs[kk][64 + tx * 4]);
#pragma unroll
      for (int i = 0; i < 8; ++i)
#pragma unroll
        for (int j = 0; j < 8; ++j) acc[i][j] = fmaf(a[i], b[j], acc[i][j]);
    }
  }

#pragma unroll
  for (int i = 0; i < 8; ++i) {
    const int m = (i < 4) ? (ty * 4 + i) : (32 + ty * 4 + (i - 4));
    const size_t r = (size_t)(row0 + m);
#pragma unroll
    for (int jh = 0; jh < 2; ++jh) {
      const int n = jh * 64 + tx * 4;
      float4 v;
      v.x = acc[i][jh * 4 + 0];
      v.y = acc[i][jh * 4 + 1];
      v.z = acc[i][jh * 4 + 2];
      v.w = acc[i][jh * 4 + 3];
      *reinterpret_cast<float4*>(&C[r * 128 + n]) = v;
    }
  }
}

// ---------------------------------------------------------------------------
// GEMM2: cur2[M][128] = s1_u8[M][128] . W2T[128][128] + b2.
// Identical structure to gemm64bt2 (full K=128, 8 steps); the ONLY change:
// A loads are uchar4 converted to float during LDS staging. float(u8 in
// {0,1}) is exact -> LDS contents and all FMA order bitwise-identical to
// the r12 fp32 GEMM2.
// ---------------------------------------------------------------------------
__global__ __launch_bounds__(128, 4) void gemm64u8(
    const unsigned char* __restrict__ A, const float* __restrict__ BT,
    const float* __restrict__ bias, float* __restrict__ C) {
  constexpr int BM = 64, BK = 16, KS = kH;
  __shared__ float As[BK][68];
  __shared__ float Bs[BK][132];
  const int tid = threadIdx.x;
  const int tx = tid & 15;
  const int ty = tid >> 4;
  const int row0 = blockIdx.x * BM;

  const int ar0 = tid >> 2;
  const int ar1 = ar0 + 32;
  const int ac4 = (tid & 3) * 4;
  const int sbk = tid >> 5;
  const int sbn4 = (tid & 31) * 4;

  const unsigned char* aptr = A + (size_t)(row0 + ar0) * KS + ac4;
  const float* btptr = BT + (size_t)sbk * 128 + sbn4;

  float acc[8][8];
#pragma unroll
  for (int i = 0; i < 8; ++i)
#pragma unroll
    for (int j = 0; j < 8; ++j) acc[i][j] = 0.0f;

  for (int s = 0; s < KS / BK; ++s) {
    const int k0 = s * BK;
    __syncthreads();
    {
      const uchar4 ua0 = *reinterpret_cast<const uchar4*>(aptr + k0);
      const uchar4 ua1 =
          *reinterpret_cast<const uchar4*>(aptr + (size_t)32 * KS + k0);
      As[ac4 + 0][ar0] = (float)ua0.x; As[ac4 + 1][ar0] = (float)ua0.y;
      As[ac4 + 2][ar0] = (float)ua0.z; As[ac4 + 3][ar0] = (float)ua0.w;
      As[ac4 + 0][ar1] = (float)ua1.x; As[ac4 + 1][ar1] = (float)ua1.y;
      As[ac4 + 2][ar1] = (float)ua1.z; As[ac4 + 3][ar1] = (float)ua1.w;
#pragma unroll
      for (int l = 0; l < 4; ++l) {
        const float4 vb = *reinterpret_cast<const float4*>(
            btptr + (size_t)(k0 + l * 4) * 128);
        *reinterpret_cast<float4*>(&Bs[sbk + l * 4][sbn4]) = vb;
      }
    }
    __syncthreads();
#pragma unroll
    for (int kk = 0; kk < BK; ++kk) {
      float a[8], b[8];
      *reinterpret_cast<float4*>(&a[0]) =
          *reinterpret_cast<const float4*>(&As[kk][ty * 4]);
      *reinterpret_cast<float4*>(&a[4]) =
          *reinterpret_cast<const float4*>(&As[kk][32 + ty * 4]);
      *reinterpret_cast<float4*>(&b[0]) =
          *reinterpret_cast<const float4*>(&Bs[kk][tx * 4]);
      *reinterpret_cast<float4*>(&b[4]) =
          *reinterpret_cast<const float4*>(&Bs[kk][64 + tx * 4]);
#pragma unroll
      for (int i = 0; i < 8; ++i)
#pragma unroll
        for (int j = 0; j < 8; ++j) acc[i][j] = fmaf(a[i], b[j], acc[i][j]);
    }
  }

#pragma unroll
  for (int i = 0; i < 8; ++i) {
    const int m = (i < 4) ? (ty * 4 + i) : (32 + ty * 4 + (i - 4));
    const size_t r = (size_t)(row0 + m);
#pragma unroll
    for (int jh = 0; jh < 2; ++jh) {
      const int n = jh * 64 + tx * 4;
      float4 v;
      v.x = acc[i][jh * 4 + 0] + bias[n + 0];
      v.y = acc[i][jh * 4 + 1] + bias[n + 1];
      v.z = acc[i][jh * 4 + 2] + bias[n + 2];
      v.w = acc[i][jh * 4 + 3] + bias[n + 3];
      *reinterpret_cast<float4*>(&C[r * 128 + n]) = v;
    }
  }
}

#define LIF_STEP(mm, ss, curexpr)                                      \
  {                                                                    \
    const float cur_ = (curexpr);                                      \
    mm = __fsub_rn(__fadd_rn(__fmul_rn(kBeta, mm), cur_), ss);         \
    ss = (mm > kThr) ? 1.0f : 0.0f;                                    \
  }

// ---------------------------------------------------------------------------
// Layer-1 LIF scan + combine: cur = (P0+P1)+b1; spikes -> S1 as u8 (exact:
// spike values are 0.0/1.0). Load pipeline proven in r12 (absmax 0.0).
// ---------------------------------------------------------------------------
__global__ __launch_bounds__(128) void lif_scan13_u8(
    const float* __restrict__ P0, const float* __restrict__ P1,
    const float* __restrict__ b1, unsigned char* __restrict__ S1) {
  const int g = blockIdx.x * 128 + threadIdx.x;  // 0..32767
  const int b = g >> 6;
  const int h2 = (g & 63) * 2;
  const size_t base = (size_t)b * kT * 128 + h2;
  const float bb0 = b1[h2], bb1 = b1[h2 + 1];
#define LD0(t) (*reinterpret_cast<const float2*>(&P0[base + (size_t)(t)*128]))
#define LD1(t) (*reinterpret_cast<const float2*>(&P1[base + (size_t)(t)*128]))
  float2 cA0 = LD0(0), cA1 = LD1(0), cB0 = LD0(1), cB1 = LD1(1);
  float2 cC0 = LD0(2), cC1 = LD1(2), cD0 = LD0(3), cD1 = LD1(3);
  float m0 = 0.f, m1 = 0.f, s0 = 0.f, s1 = 0.f;
  for (int t = 0; t < kT; t += 2) {
    const int pa = (t + 4 < kT) ? t + 4 : kT - 1;
    const int pb = (t + 5 < kT) ? t + 5 : kT - 1;
    const float2 nA0 = LD0(pa), nA1 = LD1(pa);
    const float2 nB0 = LD0(pb), nB1 = LD1(pb);
    LIF_STEP(m0, s0, __fadd_rn(__fadd_rn(cA0.x, cA1.x), bb0));
    LIF_STEP(m1, s1, __fadd_rn(__fadd_rn(cA0.y, cA1.y), bb1));
    *reinterpret_cast<uchar2*>(&S1[base + (size_t)t * 128]) =
        make_uchar2((unsigned char)s0, (unsigned char)s1);
    LIF_STEP(m0, s0, __fadd_rn(__fadd_rn(cB0.x, cB1.x), bb0));
    LIF_STEP(m1, s1, __fadd_rn(__fadd_rn(cB0.y, cB1.y), bb1));
    *reinterpret_cast<uchar2*>(&S1[base + (size_t)(t + 1) * 128]) =
        make_uchar2((unsigned char)s0, (unsigned char)s1);
    cA0 = cC0; cA1 = cC1; cB0 = cD0; cB1 = cD1;
    cC0 = nA0; cC1 = nA1; cD0 = nB0; cD1 = nB1;
  }
#undef LD0
#undef LD1
}

// ---------------------------------------------------------------------------
// Layer-2 LIF scan: reads cur2 fp32, writes u8 spikes -> S2.
// ---------------------------------------------------------------------------
__global__ __launch_bounds__(128) void lif_scan2_u8(
    const float* __restrict__ buf, unsigned char* __restrict__ S2) {
  const int g = blockIdx.x * 128 + threadIdx.x;  // 0..32767
  const int b = g >> 6;
  const int h2 = (g & 63) * 2;
  const size_t base = (size_t)b * kT * 128 + h2;
#define LD(t) (*reinterpret_cast<const float2*>(&buf[base + (size_t)(t)*128]))
  float2 cA = LD(0), cB = LD(1), cC = LD(2), cD = LD(3);
  float m0 = 0.f, m1 = 0.f, s0 = 0.f, s1 = 0.f;
  for (int t = 0; t < kT; t += 2) {
    const int pa = (t + 4 < kT) ? t + 4 : kT - 1;
    const int pb = (t + 5 < kT) ? t + 5 : kT - 1;
    const float2 nA = LD(pa), nB = LD(pb);
    LIF_STEP(m0, s0, cA.x);
    LIF_STEP(m1, s1, cA.y);
    *reinterpret_cast<uchar2*>(&S2[base + (size_t)t * 128]) =
        make_uchar2((unsigned char)s0, (unsigned char)s1);
    LIF_STEP(m0, s0, cB.x);
    LIF_STEP(m1, s1, cB.y);
    *reinterpret_cast<uchar2*>(&S2[base + (size_t)(t + 1) * 128]) =
        make_uchar2((unsigned char)s0, (unsigned char)s1);
    cA = cC; cB = cD; cC = nA; cD = nB;
  }
#undef LD
}

// ---------------------------------------------------------------------------
// GEMM3: cur3[M][10] = s2_u8[M][128] . W3[10][128]^T + b3. Same as the
// proven gemm3_n10 except A staged from u8 (exact conversion).
// ---------------------------------------------------------------------------
__global__ __launch_bounds__(320) void gemm3_u8(
    const unsigned char* __restrict__ A, const float* __restrict__ W3,
    const float* __restrict__ b3, float* __restrict__ C) {
  __shared__ float Ss[64][132];
  __shared__ float Ws[10][132];
  __shared__ float bs[10];
  const int tid = threadIdx.x;
  const size_t row0 = (size_t)blockIdx.x * 64;

  {
    const int r = tid >> 5;
    const int c4 = (tid & 31) * 4;
    const float4 v = *reinterpret_cast<const float4*>(&W3[r * 128 + c4]);
    Ws[r][c4 + 0] = v.x;
    Ws[r][c4 + 1] = v.y;
    Ws[r][c4 + 2] = v.z;
    Ws[r][c4 + 3] = v.w;
    if (tid < 10) bs[tid] = b3[tid];
  }
  for (int fi = tid; fi < 2048; fi += 320) {
    const int r = fi >> 5;
    const int c4 = (fi & 31) * 4;
    const uchar4 v =
        *reinterpret_cast<const uchar4*>(&A[(row0 + r) * 128 + c4]);
    Ss[r][c4 + 0] = (float)v.x;
    Ss[r][c4 + 1] = (float)v.y;
    Ss[r][c4 + 2] = (float)v.z;
    Ss[r][c4 + 3] = (float)v.w;
  }
  __syncthreads();

#pragma unroll
  for (int l = 0; l < 2; ++l) {
    const int idx = tid + l * 320;
    const int r = idx / 10;
    const int o = idx - r * 10;
    float acc = bs[o];
#pragma unroll
    for (int k = 0; k < 128; k += 4) {
      const float4 a = *reinterpret_cast<const float4*>(&Ss[r][k]);
      const float4 w = *reinterpret_cast<const float4*>(&Ws[o][k]);
      acc = fmaf(a.x, w.x, acc);
      acc = fmaf(a.y, w.y, acc);
      acc = fmaf(a.z, w.z, acc);
      acc = fmaf(a.w, w.w, acc);
    }
    C[(row0 + r) * 10 + o] = acc;
  }
}

// ---------------------------------------------------------------------------
// Output LIF scan -> out[t][b][o]. (unchanged, proven)
// ---------------------------------------------------------------------------
__global__ __launch_bounds__(256) void lif_scan_out(
    const float* __restrict__ cur3, float* __restrict__ out) {
  const int g = blockIdx.x * 256 + threadIdx.x;  // 0..5119
  if (g >= kB * kO) return;
  const int b = g / kO;
  const int o = g - b * kO;
  float m = 0.0f, s = 0.0f;
#pragma unroll 4
  for (int t = 0; t < kT; ++t) {
    const float c = cur3[((size_t)b * kT + t) * kO + o];
    m = __fsub_rn(__fadd_rn(__fmul_rn(kBeta, m), c), s);
    s = (m > kThr) ? 1.0f : 0.0f;
    out[(size_t)t * (kB * kO) + g] = s;
  }
}

extern "C" void kernel_launch(void* const* d_in, const int* in_sizes, int n_in,
                              void* d_out, int out_size, void* d_ws,
                              size_t ws_size, hipStream_t stream) {
  (void)in_sizes;
  (void)n_in;
  (void)out_size;
  (void)ws_size;
  const float* x = (const float*)d_in[0];    // [B,T,784]
  const float* W1 = (const float*)d_in[1];   // [128,784]
  const float* b1 = (const float*)d_in[2];   // [128]
  const float* W2 = (const float*)d_in[3];   // [128,128]
  const float* b2 = (const float*)d_in[4];   // [128]
  const float* W3 = (const float*)d_in[5];   // [10,128]
  const float* b3 = (const float*)d_in[6];   // [10]
  float* out = (float*)d_out;                // [T,B,10] = 4.1 MB

  const size_t bufElems = (size_t)kM * kH;   // 13.1M elems
  float* P0 = (float*)d_ws;                  // partial0 -> cur2
  float* P1 = P0 + bufElems;                 // partial1 -> cur3
  unsigned char* S1 = (unsigned char*)(P1 + bufElems);  // s1 u8, 13.1 MB
  unsigned char* S2 = S1 + bufElems;                    // s2 u8, 13.1 MB
  // total ws use: 131 MB (r16 confirmed ws >= 210 MB)

  // W1T + W2T (467 KB) stashed at head of d_out; overwritten by the final
  // lif_scan_out (proven r10-r16 pattern).
  float* W1T = out;
  float* W2T = W1T + (size_t)kI * kH;

  transposeW<<<dim3(kI / 16, kH / 16), 256, 0, stream>>>(W1, W1T, kH, kI);
  transposeW<<<dim3(kH / 16, kH / 16), 256, 0, stream>>>(W2, W2T, kH, kH);

  // Layer 1: 2-way split-K GEMM (r12 config), partials P0,P1; scan -> S1 u8.
  gemm64bt2<<<2 * (kM / 64), 128, 0, stream>>>(x, W1T, P0, bufElems);
  lif_scan13_u8<<<256, 128, 0, stream>>>(P0, P1, b1, S1);
  // Layer 2: full-K u8-A GEMM, bias fused; cur2 -> P0; scan -> S2 u8.
  gemm64u8<<<kM / 64, 128, 0, stream>>>(S1, W2T, b2, P0);
  lif_scan2_u8<<<256, 128, 0, stream>>>(P0, S2);
  // Layer 3: cur3 -> P1; final scan -> out.
  gemm3_u8<<<kM / 64, 320, 0, stream>>>(S2, W3, b3, P1);
  lif_scan_out<<<(kB * kO + 255) / 256, 256, 0, stream>>>(P1, out);
}